// Round 3
// baseline (310.451 us; speedup 1.0000x reference)
//
#include <hip/hip_runtime.h>
#include <math.h>

#define H 1024
#define B 64
#define L 2048

#define GC 32   // g-chunks (32 g each)
#define HC 4    // h-chunks (256 h each)
#define BG 8    // b-groups (8 b per thread)

typedef float f32x4 __attribute__((ext_vector_type(4)));

__device__ inline f32x4 nt_load4(const f32x4* p) {
    return __builtin_nontemporal_load(p);
}

// ---------------------------------------------------------------------------
// Kernel 1a: partial[b][gc][h] = sum_{g in chunk gc} hidden[b,g] * W[g,h]
// grid (GC, HC, BG) = 1024 blocks (4/CU). Thread owns one h, 8 b's in regs.
// hidden reads are wave-uniform -> scalar loads. Block 0 also zeroes the
// per-b softmax counters (visible to the scores kernel via kernel boundary).
// ---------------------------------------------------------------------------
__global__ __launch_bounds__(256) void u_partial_kernel(
        const float* __restrict__ hidden,
        const float* __restrict__ W,
        float* __restrict__ partial,
        int* __restrict__ counters) {
    if (blockIdx.x == 0 && blockIdx.y == 0 && blockIdx.z == 0 &&
        threadIdx.x < B) {
        counters[threadIdx.x] = 0;
    }

    const int h  = blockIdx.y * 256 + threadIdx.x;
    const int g0 = blockIdx.x * 32;
    const int b0 = blockIdx.z * 8;

    float acc[8];
#pragma unroll
    for (int bb = 0; bb < 8; ++bb) acc[bb] = 0.f;

#pragma unroll 4
    for (int gg = 0; gg < 32; ++gg) {
        const int g = g0 + gg;
        const float w = W[(size_t)g * H + h];
#pragma unroll
        for (int bb = 0; bb < 8; ++bb) {
            acc[bb] = fmaf(hidden[(b0 + bb) * H + g], w, acc[bb]);
        }
    }

#pragma unroll
    for (int bb = 0; bb < 8; ++bb) {
        partial[((size_t)(b0 + bb) * GC + blockIdx.x) * H + h] = acc[bb];
    }
}

// ---------------------------------------------------------------------------
// Kernel 1b: u[b][h] = sum_gc partial[b][gc][h]. 8 MB read, 256 blocks.
// ---------------------------------------------------------------------------
__global__ __launch_bounds__(256) void u_reduce_kernel(
        const float* __restrict__ partial,
        float* __restrict__ u) {
    const int idx = blockIdx.x * 256 + threadIdx.x;   // b*H + h
    const int b = idx >> 10;
    const int h = idx & (H - 1);
    float s = 0.f;
#pragma unroll
    for (int gc = 0; gc < GC; ++gc) {
        s += partial[((size_t)b * GC + gc) * H + h];
    }
    u[idx] = s;
}

// ---------------------------------------------------------------------------
// Kernel 2: scores + fused softmax (last-arriver-per-b pattern).
// Block x: b = x & 63, lc = x >> 6. Block covers l in [lc*32, lc*32+32);
// wave w handles 8 l's with u row cached in 16 VGPRs. enc reads are
// non-temporal (zero reuse -> don't evict u/W from L2).
// After its chunk is written: threadfence + atomicAdd(counter[b]); the
// 64th block to finish b softmaxes the whole row (8 KB, L2-hot).
// Output identical regardless of which block wins -> deterministic.
// ---------------------------------------------------------------------------
#define ITER 8
__global__ __launch_bounds__(256) void scores_softmax_kernel(
        const f32x4* __restrict__ enc4,
        const f32x4* __restrict__ u4,
        float* __restrict__ out,
        int* __restrict__ counters) {
    const int b    = blockIdx.x & (B - 1);
    const int lc   = blockIdx.x >> 6;
    const int wave = threadIdx.x >> 6;
    const int lane = threadIdx.x & 63;
    const int l0   = lc * 32 + wave * ITER;

    const f32x4* __restrict__ uu = u4 + (size_t)b * (H / 4);
    const f32x4 uv0 = uu[lane];
    const f32x4 uv1 = uu[64 + lane];
    const f32x4 uv2 = uu[128 + lane];
    const f32x4 uv3 = uu[192 + lane];

    const f32x4* __restrict__ e = enc4 + ((size_t)l0 * B + b) * (H / 4);

    float acc[ITER];
#pragma unroll
    for (int i = 0; i < ITER; ++i) {
        const f32x4* __restrict__ ei = e + (size_t)i * B * (H / 4);
        const f32x4 e0 = nt_load4(ei + lane);
        const f32x4 e1 = nt_load4(ei + 64 + lane);
        const f32x4 e2 = nt_load4(ei + 128 + lane);
        const f32x4 e3 = nt_load4(ei + 192 + lane);
        float a = e0.x * uv0.x;
        a = fmaf(e0.y, uv0.y, a);
        a = fmaf(e0.z, uv0.z, a);
        a = fmaf(e0.w, uv0.w, a);
        a = fmaf(e1.x, uv1.x, a);
        a = fmaf(e1.y, uv1.y, a);
        a = fmaf(e1.z, uv1.z, a);
        a = fmaf(e1.w, uv1.w, a);
        a = fmaf(e2.x, uv2.x, a);
        a = fmaf(e2.y, uv2.y, a);
        a = fmaf(e2.z, uv2.z, a);
        a = fmaf(e2.w, uv2.w, a);
        a = fmaf(e3.x, uv3.x, a);
        a = fmaf(e3.y, uv3.y, a);
        a = fmaf(e3.z, uv3.z, a);
        a = fmaf(e3.w, uv3.w, a);
        acc[i] = a;
    }

#pragma unroll
    for (int i = 0; i < ITER; ++i) {
#pragma unroll
        for (int off = 32; off; off >>= 1) acc[i] += __shfl_down(acc[i], off);
    }

    if (lane == 0) {
        float4* dst = (float4*)(out + (size_t)b * L + l0);
        dst[0] = make_float4(acc[0], acc[1], acc[2], acc[3]);
        dst[1] = make_float4(acc[4], acc[5], acc[6], acc[7]);
    }

    // ---- last-arriver softmax over row b ----
    __shared__ int winner;
    __shared__ float redm[4];
    __shared__ float reds[4];

    __syncthreads();
    if (threadIdx.x == 0) {
        __threadfence();
        const int old = atomicAdd(&counters[b], 1);
        winner = (old == 63) ? 1 : 0;
    }
    __syncthreads();
    if (!winner) return;

    __threadfence();
    float4* __restrict__ r4 = (float4*)(out + (size_t)b * L);
    const int tid = threadIdx.x;
    float4 a0 = r4[tid];
    float4 a1 = r4[256 + tid];

    float m = fmaxf(fmaxf(fmaxf(a0.x, a0.y), fmaxf(a0.z, a0.w)),
                    fmaxf(fmaxf(a1.x, a1.y), fmaxf(a1.z, a1.w)));
#pragma unroll
    for (int off = 32; off; off >>= 1) m = fmaxf(m, __shfl_down(m, off));
    if (lane == 0) redm[wave] = m;
    __syncthreads();
    m = fmaxf(fmaxf(redm[0], redm[1]), fmaxf(redm[2], redm[3]));

    float e0 = expf(a0.x - m), e1 = expf(a0.y - m);
    float e2 = expf(a0.z - m), e3 = expf(a0.w - m);
    float e4 = expf(a1.x - m), e5 = expf(a1.y - m);
    float e6 = expf(a1.z - m), e7 = expf(a1.w - m);

    float s = ((e0 + e1) + (e2 + e3)) + ((e4 + e5) + (e6 + e7));
#pragma unroll
    for (int off = 32; off; off >>= 1) s += __shfl_down(s, off);
    if (lane == 0) reds[wave] = s;
    __syncthreads();
    s = (reds[0] + reds[1]) + (reds[2] + reds[3]);

    const float inv = 1.f / s;
    a0.x = e0 * inv; a0.y = e1 * inv; a0.z = e2 * inv; a0.w = e3 * inv;
    a1.x = e4 * inv; a1.y = e5 * inv; a1.z = e6 * inv; a1.w = e7 * inv;
    r4[tid]       = a0;
    r4[256 + tid] = a1;
}

extern "C" void kernel_launch(void* const* d_in, const int* in_sizes, int n_in,
                              void* d_out, int out_size, void* d_ws, size_t ws_size,
                              hipStream_t stream) {
    const float* hidden = (const float*)d_in[0];  // [B, H]
    const float* enc    = (const float*)d_in[1];  // [L, B, H]
    const float* W      = (const float*)d_in[2];  // [H, H]
    // d_in[3] (bias) cancels in the softmax over l — provably irrelevant.

    float* u       = (float*)d_ws;                        // [B, H]       256 KB
    float* partial = (float*)d_ws + (size_t)B * H;        // [B, GC, H]   8 MB
    int* counters  = (int*)((float*)d_ws + (size_t)B * H + (size_t)B * GC * H);
    float* out     = (float*)d_out;                       // [B, 1, L]    fp32

    // 1) u = hidden @ W (partial + reduce); also zeroes softmax counters
    u_partial_kernel<<<dim3(GC, HC, BG), 256, 0, stream>>>(hidden, W, partial,
                                                           counters);
    u_reduce_kernel<<<(B * H) / 256, 256, 0, stream>>>(partial, u);

    // 2) scores + in-place fused softmax
    scores_softmax_kernel<<<B * (L / 32), 256, 0, stream>>>(
        (const f32x4*)enc, (const f32x4*)u, out, counters);
}

// Round 4
// 117.061 us; speedup vs baseline: 2.6520x; 2.6520x over previous
//
#include <hip/hip_runtime.h>
#include <math.h>

#define H 1024
#define B 64
#define L 2048

#define GC 32   // g-chunks (32 g each)
#define HC 4    // h-chunks (256 h each)
#define BG 8    // b-groups (8 b per thread)

// ---------------------------------------------------------------------------
// Kernel 1a: partial[b][gc][h] = sum_{g in chunk gc} hidden[b,g] * W[g,h]
// grid (GC, HC, BG) = 1024 blocks (4/CU). Thread owns one h, 8 b's in regs.
// hidden reads are wave-uniform -> scalar loads feeding v_fmac directly.
// ---------------------------------------------------------------------------
__global__ __launch_bounds__(256) void u_partial_kernel(
        const float* __restrict__ hidden,
        const float* __restrict__ W,
        float* __restrict__ partial) {
    const int h  = blockIdx.y * 256 + threadIdx.x;
    const int g0 = blockIdx.x * 32;
    const int b0 = blockIdx.z * 8;

    float acc[8];
#pragma unroll
    for (int bb = 0; bb < 8; ++bb) acc[bb] = 0.f;

#pragma unroll 4
    for (int gg = 0; gg < 32; ++gg) {
        const int g = g0 + gg;
        const float w = W[(size_t)g * H + h];
#pragma unroll
        for (int bb = 0; bb < 8; ++bb) {
            acc[bb] = fmaf(hidden[(b0 + bb) * H + g], w, acc[bb]);
        }
    }

#pragma unroll
    for (int bb = 0; bb < 8; ++bb) {
        partial[((size_t)(b0 + bb) * GC + blockIdx.x) * H + h] = acc[bb];
    }
}

// ---------------------------------------------------------------------------
// Kernel 1b: u[b][h] = sum_gc partial[b][gc][h]. 8 MB read, 256 blocks.
// ---------------------------------------------------------------------------
__global__ __launch_bounds__(256) void u_reduce_kernel(
        const float* __restrict__ partial,
        float* __restrict__ u) {
    const int idx = blockIdx.x * 256 + threadIdx.x;   // b*H + h
    const int b = idx >> 10;
    const int h = idx & (H - 1);
    float s = 0.f;
#pragma unroll
    for (int gc = 0; gc < GC; ++gc) {
        s += partial[((size_t)b * GC + gc) * H + h];
    }
    u[idx] = s;
}

// ---------------------------------------------------------------------------
// Kernel 2: scores[b,l] = dot(enc[l,b,:], u[b,:]).
// One wave handles ITER=16 consecutive l's for a FIXED b; u row (4 KB) lives
// in 16 VGPRs. Streaming loop kept at unroll-4 so ~16 enc loads stay in
// flight per wave without blowing VGPR past the 4-waves/SIMD cliff.
// enc reads: 4x float4 per l, each a contiguous 1 KB wave transaction.
// ---------------------------------------------------------------------------
#define ITER 16
__global__ __launch_bounds__(256) void scores_kernel(
        const float4* __restrict__ enc4,
        const float4* __restrict__ u4,
        float* __restrict__ scores) {
    const int wave = threadIdx.x >> 6;
    const int lane = threadIdx.x & 63;
    const int gw   = blockIdx.x * 4 + wave;        // [0, B*L/ITER)
    const int b    = gw & (B - 1);
    const int l0   = (gw >> 6) * ITER;

    const float4* __restrict__ uu = u4 + (size_t)b * (H / 4);
    const float4 uv0 = uu[lane];
    const float4 uv1 = uu[64 + lane];
    const float4 uv2 = uu[128 + lane];
    const float4 uv3 = uu[192 + lane];

    const float4* __restrict__ e = enc4 + ((size_t)l0 * B + b) * (H / 4);

    float acc[ITER];
#pragma unroll 4
    for (int i = 0; i < ITER; ++i) {
        const float4* __restrict__ ei = e + (size_t)i * B * (H / 4);
        const float4 e0 = ei[lane];
        const float4 e1 = ei[64 + lane];
        const float4 e2 = ei[128 + lane];
        const float4 e3 = ei[192 + lane];
        float a = e0.x * uv0.x;
        a = fmaf(e0.y, uv0.y, a);
        a = fmaf(e0.z, uv0.z, a);
        a = fmaf(e0.w, uv0.w, a);
        a = fmaf(e1.x, uv1.x, a);
        a = fmaf(e1.y, uv1.y, a);
        a = fmaf(e1.z, uv1.z, a);
        a = fmaf(e1.w, uv1.w, a);
        a = fmaf(e2.x, uv2.x, a);
        a = fmaf(e2.y, uv2.y, a);
        a = fmaf(e2.z, uv2.z, a);
        a = fmaf(e2.w, uv2.w, a);
        a = fmaf(e3.x, uv3.x, a);
        a = fmaf(e3.y, uv3.y, a);
        a = fmaf(e3.z, uv3.z, a);
        a = fmaf(e3.w, uv3.w, a);
        acc[i] = a;
    }

#pragma unroll
    for (int i = 0; i < ITER; ++i) {
#pragma unroll
        for (int off = 32; off; off >>= 1) acc[i] += __shfl_down(acc[i], off);
    }

    if (lane == 0) {
        float4* dst = (float4*)(scores + (size_t)b * L + l0);
        dst[0] = make_float4(acc[0],  acc[1],  acc[2],  acc[3]);
        dst[1] = make_float4(acc[4],  acc[5],  acc[6],  acc[7]);
        dst[2] = make_float4(acc[8],  acc[9],  acc[10], acc[11]);
        dst[3] = make_float4(acc[12], acc[13], acc[14], acc[15]);
    }
}

// ---------------------------------------------------------------------------
// Kernel 3: in-place row softmax, one block (512 threads) per b, 1 float4/thr.
// ---------------------------------------------------------------------------
__global__ __launch_bounds__(512) void softmax_kernel(float* __restrict__ out) {
    __shared__ float redm[8];
    __shared__ float reds[8];
    const int b    = blockIdx.x;
    const int tid  = threadIdx.x;
    const int wave = tid >> 6;
    const int lane = tid & 63;

    float4* __restrict__ r4 = (float4*)(out + (size_t)b * L);
    float4 a = r4[tid];

    float m = fmaxf(fmaxf(a.x, a.y), fmaxf(a.z, a.w));
#pragma unroll
    for (int off = 32; off; off >>= 1) m = fmaxf(m, __shfl_down(m, off));
    if (lane == 0) redm[wave] = m;
    __syncthreads();
    m = fmaxf(fmaxf(fmaxf(redm[0], redm[1]), fmaxf(redm[2], redm[3])),
              fmaxf(fmaxf(redm[4], redm[5]), fmaxf(redm[6], redm[7])));

    float e0 = expf(a.x - m), e1 = expf(a.y - m);
    float e2 = expf(a.z - m), e3 = expf(a.w - m);

    float s = (e0 + e1) + (e2 + e3);
#pragma unroll
    for (int off = 32; off; off >>= 1) s += __shfl_down(s, off);
    if (lane == 0) reds[wave] = s;
    __syncthreads();
    s = ((reds[0] + reds[1]) + (reds[2] + reds[3])) +
        ((reds[4] + reds[5]) + (reds[6] + reds[7]));

    const float inv = 1.f / s;
    a.x = e0 * inv; a.y = e1 * inv; a.z = e2 * inv; a.w = e3 * inv;
    r4[tid] = a;
}

extern "C" void kernel_launch(void* const* d_in, const int* in_sizes, int n_in,
                              void* d_out, int out_size, void* d_ws, size_t ws_size,
                              hipStream_t stream) {
    const float* hidden = (const float*)d_in[0];  // [B, H]
    const float* enc    = (const float*)d_in[1];  // [L, B, H]
    const float* W      = (const float*)d_in[2];  // [H, H]
    // d_in[3] (bias) cancels in the softmax over l — provably irrelevant.

    float* u       = (float*)d_ws;                        // [B, H]      256 KB
    float* partial = (float*)d_ws + (size_t)B * H;        // [B, GC, H]  8 MB
    float* out     = (float*)d_out;                       // [B, 1, L]   fp32

    // 1) u = hidden @ W (partial + reduce)
    u_partial_kernel<<<dim3(GC, HC, BG), 256, 0, stream>>>(hidden, W, partial);
    u_reduce_kernel<<<(B * H) / 256, 256, 0, stream>>>(partial, u);

    // 2) scores[b,l] = dot(enc[l,b,:], u[b,:]) -> d_out
    scores_kernel<<<(B * L / ITER) / 4, 256, 0, stream>>>(
        (const float4*)enc, (const float4*)u, out);

    // 3) softmax over l, in place
    softmax_kernel<<<B, 512, 0, stream>>>(out);
}

// Round 5
// 108.009 us; speedup vs baseline: 2.8743x; 1.0838x over previous
//
#include <hip/hip_runtime.h>
#include <math.h>

#define H 1024
#define B 64
#define L 2048

#define GC 64   // g-chunks (16 g each)
#define HC 4    // h-chunks (256 h each)
#define BG 8    // b-groups (8 b per thread)

typedef float f32x4 __attribute__((ext_vector_type(4)));

// ---------------------------------------------------------------------------
// Kernel 1a: partial[b][gc][h] = sum_{g in chunk gc} hidden[b,g] * W[g,h]
// grid (GC, HC, BG) = 2048 blocks (8/CU). Thread owns one h, 8 b's in regs.
// 16 g-iters, unroll 8 -> 2 latency stall-groups. hidden reads wave-uniform
// -> scalar loads feeding v_fmac directly.
// ---------------------------------------------------------------------------
__global__ __launch_bounds__(256) void u_partial_kernel(
        const float* __restrict__ hidden,
        const float* __restrict__ W,
        float* __restrict__ partial) {
    const int h  = blockIdx.y * 256 + threadIdx.x;
    const int g0 = blockIdx.x * 16;
    const int b0 = blockIdx.z * 8;

    float acc[8];
#pragma unroll
    for (int bb = 0; bb < 8; ++bb) acc[bb] = 0.f;

#pragma unroll 8
    for (int gg = 0; gg < 16; ++gg) {
        const int g = g0 + gg;
        const float w = W[(size_t)g * H + h];
#pragma unroll
        for (int bb = 0; bb < 8; ++bb) {
            acc[bb] = fmaf(hidden[(b0 + bb) * H + g], w, acc[bb]);
        }
    }

#pragma unroll
    for (int bb = 0; bb < 8; ++bb) {
        partial[((size_t)(b0 + bb) * GC + blockIdx.x) * H + h] = acc[bb];
    }
}

// ---------------------------------------------------------------------------
// Kernel 1b: u[b][h] = sum_gc partial[b][gc][h]. 16 MB read (L2/L3-hot).
// ---------------------------------------------------------------------------
__global__ __launch_bounds__(256) void u_reduce_kernel(
        const float* __restrict__ partial,
        float* __restrict__ u) {
    const int idx = blockIdx.x * 256 + threadIdx.x;   // b*H + h
    const int b = idx >> 10;
    const int h = idx & (H - 1);
    float s = 0.f;
#pragma unroll 16
    for (int gc = 0; gc < GC; ++gc) {
        s += partial[((size_t)b * GC + gc) * H + h];
    }
    u[idx] = s;
}

// ---------------------------------------------------------------------------
// Kernel 2: scores[b,l] = dot(enc[l,b,:], u[b,:]).
// One wave handles ITER=32 consecutive l's for a FIXED b; u row (4 KB) lives
// in 16 VGPRs (cached loads). enc is streamed with NON-TEMPORAL loads: zero
// reuse, so don't let the 512 MB stream evict u/W from L2. unroll 2 keeps
// 8 x 1 KB wave-loads in flight; grid = 1024 blocks = fully co-resident,
// each CU streams exactly 2 MB.
// ---------------------------------------------------------------------------
#define ITER 32
__global__ __launch_bounds__(256) void scores_kernel(
        const f32x4* __restrict__ enc4,
        const f32x4* __restrict__ u4,
        float* __restrict__ scores) {
    const int wave = threadIdx.x >> 6;
    const int lane = threadIdx.x & 63;
    const int gw   = blockIdx.x * 4 + wave;        // [0, B*L/ITER)
    const int b    = gw & (B - 1);
    const int l0   = (gw >> 6) * ITER;

    const f32x4* __restrict__ uu = u4 + (size_t)b * (H / 4);
    const f32x4 uv0 = uu[lane];
    const f32x4 uv1 = uu[64 + lane];
    const f32x4 uv2 = uu[128 + lane];
    const f32x4 uv3 = uu[192 + lane];

    const f32x4* __restrict__ e = enc4 + ((size_t)l0 * B + b) * (H / 4);

    float acc[ITER];
#pragma unroll 2
    for (int i = 0; i < ITER; ++i) {
        const f32x4* __restrict__ ei = e + (size_t)i * B * (H / 4);
        const f32x4 e0 = __builtin_nontemporal_load(ei + lane);
        const f32x4 e1 = __builtin_nontemporal_load(ei + 64 + lane);
        const f32x4 e2 = __builtin_nontemporal_load(ei + 128 + lane);
        const f32x4 e3 = __builtin_nontemporal_load(ei + 192 + lane);
        float a = e0.x * uv0.x;
        a = fmaf(e0.y, uv0.y, a);
        a = fmaf(e0.z, uv0.z, a);
        a = fmaf(e0.w, uv0.w, a);
        a = fmaf(e1.x, uv1.x, a);
        a = fmaf(e1.y, uv1.y, a);
        a = fmaf(e1.z, uv1.z, a);
        a = fmaf(e1.w, uv1.w, a);
        a = fmaf(e2.x, uv2.x, a);
        a = fmaf(e2.y, uv2.y, a);
        a = fmaf(e2.z, uv2.z, a);
        a = fmaf(e2.w, uv2.w, a);
        a = fmaf(e3.x, uv3.x, a);
        a = fmaf(e3.y, uv3.y, a);
        a = fmaf(e3.z, uv3.z, a);
        a = fmaf(e3.w, uv3.w, a);
        acc[i] = a;
    }

#pragma unroll
    for (int i = 0; i < ITER; ++i) {
#pragma unroll
        for (int off = 32; off; off >>= 1) acc[i] += __shfl_down(acc[i], off);
    }

    if (lane == 0) {
        float4* dst = (float4*)(scores + (size_t)b * L + l0);
#pragma unroll
        for (int q = 0; q < ITER / 4; ++q) {
            dst[q] = make_float4(acc[4 * q], acc[4 * q + 1],
                                 acc[4 * q + 2], acc[4 * q + 3]);
        }
    }
}

// ---------------------------------------------------------------------------
// Kernel 3: in-place row softmax, one block (512 threads) per b, 1 float4/thr.
// ---------------------------------------------------------------------------
__global__ __launch_bounds__(512) void softmax_kernel(float* __restrict__ out) {
    __shared__ float redm[8];
    __shared__ float reds[8];
    const int b    = blockIdx.x;
    const int tid  = threadIdx.x;
    const int wave = tid >> 6;
    const int lane = tid & 63;

    float4* __restrict__ r4 = (float4*)(out + (size_t)b * L);
    float4 a = r4[tid];

    float m = fmaxf(fmaxf(a.x, a.y), fmaxf(a.z, a.w));
#pragma unroll
    for (int off = 32; off; off >>= 1) m = fmaxf(m, __shfl_down(m, off));
    if (lane == 0) redm[wave] = m;
    __syncthreads();
    m = fmaxf(fmaxf(fmaxf(redm[0], redm[1]), fmaxf(redm[2], redm[3])),
              fmaxf(fmaxf(redm[4], redm[5]), fmaxf(redm[6], redm[7])));

    float e0 = expf(a.x - m), e1 = expf(a.y - m);
    float e2 = expf(a.z - m), e3 = expf(a.w - m);

    float s = (e0 + e1) + (e2 + e3);
#pragma unroll
    for (int off = 32; off; off >>= 1) s += __shfl_down(s, off);
    if (lane == 0) reds[wave] = s;
    __syncthreads();
    s = ((reds[0] + reds[1]) + (reds[2] + reds[3])) +
        ((reds[4] + reds[5]) + (reds[6] + reds[7]));

    const float inv = 1.f / s;
    a.x = e0 * inv; a.y = e1 * inv; a.z = e2 * inv; a.w = e3 * inv;
    r4[tid] = a;
}

extern "C" void kernel_launch(void* const* d_in, const int* in_sizes, int n_in,
                              void* d_out, int out_size, void* d_ws, size_t ws_size,
                              hipStream_t stream) {
    const float* hidden = (const float*)d_in[0];  // [B, H]
    const float* enc    = (const float*)d_in[1];  // [L, B, H]
    const float* W      = (const float*)d_in[2];  // [H, H]
    // d_in[3] (bias) cancels in the softmax over l — provably irrelevant.

    float* u       = (float*)d_ws;                        // [B, H]      256 KB
    float* partial = (float*)d_ws + (size_t)B * H;        // [B, GC, H]  16 MB
    float* out     = (float*)d_out;                       // [B, 1, L]   fp32

    // 1) u = hidden @ W (partial + reduce)
    u_partial_kernel<<<dim3(GC, HC, BG), 256, 0, stream>>>(hidden, W, partial);
    u_reduce_kernel<<<(B * H) / 256, 256, 0, stream>>>(partial, u);

    // 2) scores[b,l] = dot(enc[l,b,:], u[b,:]) -> d_out
    scores_kernel<<<(B * L / ITER) / 4, 256, 0, stream>>>(
        (const f32x4*)enc, (const f32x4*)u, out);

    // 3) softmax over l, in place
    softmax_kernel<<<B, 512, 0, stream>>>(out);
}

// Round 6
// 101.004 us; speedup vs baseline: 3.0737x; 1.0694x over previous
//
#include <hip/hip_runtime.h>
#include <math.h>

#define H 1024
#define B 64
#define L 2048

#define GC 32   // g-chunks (32 g each)
#define HC 4    // h-chunks (256 h each)
#define BG 8    // b-groups (8 b per thread)

typedef float f32x4 __attribute__((ext_vector_type(4)));

// ---------------------------------------------------------------------------
// Kernel 1a: partial[b][gc][h] = sum_{g in chunk gc} hidden[b,g] * W[g,h]
// grid (GC, HC, BG) = 1024 blocks (4/CU). Thread owns one h, 8 b's in regs.
// 32 g-iters, unroll 8. hidden reads wave-uniform -> scalar loads.
// ---------------------------------------------------------------------------
__global__ __launch_bounds__(256) void u_partial_kernel(
        const float* __restrict__ hidden,
        const float* __restrict__ W,
        float* __restrict__ partial) {
    const int h  = blockIdx.y * 256 + threadIdx.x;
    const int g0 = blockIdx.x * 32;
    const int b0 = blockIdx.z * 8;

    float acc[8];
#pragma unroll
    for (int bb = 0; bb < 8; ++bb) acc[bb] = 0.f;

#pragma unroll 8
    for (int gg = 0; gg < 32; ++gg) {
        const int g = g0 + gg;
        const float w = W[(size_t)g * H + h];
#pragma unroll
        for (int bb = 0; bb < 8; ++bb) {
            acc[bb] = fmaf(hidden[(b0 + bb) * H + g], w, acc[bb]);
        }
    }

#pragma unroll
    for (int bb = 0; bb < 8; ++bb) {
        partial[((size_t)(b0 + bb) * GC + blockIdx.x) * H + h] = acc[bb];
    }
}

// ---------------------------------------------------------------------------
// Kernel 1b: u[b][h] = sum_gc partial[b][gc][h]. 8 MB read (L2-hot).
// ---------------------------------------------------------------------------
__global__ __launch_bounds__(256) void u_reduce_kernel(
        const float* __restrict__ partial,
        float* __restrict__ u) {
    const int idx = blockIdx.x * 256 + threadIdx.x;   // b*H + h
    const int b = idx >> 10;
    const int h = idx & (H - 1);
    float s = 0.f;
#pragma unroll 16
    for (int gc = 0; gc < GC; ++gc) {
        s += partial[((size_t)b * GC + gc) * H + h];
    }
    u[idx] = s;
}

// ---------------------------------------------------------------------------
// Kernel 2: scores[b,l] = dot(enc[l,b,:], u[b,:]).
// One wave: ITER=32 consecutive l's for fixed b; u row in 16 VGPRs; enc
// streamed non-temporal (zero reuse). Reduction via LDS transpose:
//   write acc[q] -> red[wave][lane][q]  ([64][33] pad: bank=(L+q)%32, 2-way)
//   lane a sums column a over its 32-row half (bank=(r+L)%32, conflict-free)
//   shfl_xor(32) merges halves; lanes 0-31 do ONE coalesced 128 B store.
// DS ops/wave: 65 vs 192 for the old per-acc butterflies.
// ---------------------------------------------------------------------------
#define ITER 32
__global__ __launch_bounds__(256, 4) void scores_kernel(
        const f32x4* __restrict__ enc4,
        const f32x4* __restrict__ u4,
        float* __restrict__ scores) {
    __shared__ float red[4][64][33];
    const int wave = threadIdx.x >> 6;
    const int lane = threadIdx.x & 63;
    const int gw   = blockIdx.x * 4 + wave;        // [0, B*L/ITER)
    const int b    = gw & (B - 1);
    const int l0   = (gw >> 6) * ITER;

    const f32x4* __restrict__ uu = u4 + (size_t)b * (H / 4);
    const f32x4 uv0 = uu[lane];
    const f32x4 uv1 = uu[64 + lane];
    const f32x4 uv2 = uu[128 + lane];
    const f32x4 uv3 = uu[192 + lane];

    const f32x4* __restrict__ e = enc4 + ((size_t)l0 * B + b) * (H / 4);

    float acc[ITER];
#pragma unroll 2
    for (int i = 0; i < ITER; ++i) {
        const f32x4* __restrict__ ei = e + (size_t)i * B * (H / 4);
        const f32x4 e0 = __builtin_nontemporal_load(ei + lane);
        const f32x4 e1 = __builtin_nontemporal_load(ei + 64 + lane);
        const f32x4 e2 = __builtin_nontemporal_load(ei + 128 + lane);
        const f32x4 e3 = __builtin_nontemporal_load(ei + 192 + lane);
        float a = e0.x * uv0.x;
        a = fmaf(e0.y, uv0.y, a);
        a = fmaf(e0.z, uv0.z, a);
        a = fmaf(e0.w, uv0.w, a);
        a = fmaf(e1.x, uv1.x, a);
        a = fmaf(e1.y, uv1.y, a);
        a = fmaf(e1.z, uv1.z, a);
        a = fmaf(e1.w, uv1.w, a);
        a = fmaf(e2.x, uv2.x, a);
        a = fmaf(e2.y, uv2.y, a);
        a = fmaf(e2.z, uv2.z, a);
        a = fmaf(e2.w, uv2.w, a);
        a = fmaf(e3.x, uv3.x, a);
        a = fmaf(e3.y, uv3.y, a);
        a = fmaf(e3.z, uv3.z, a);
        a = fmaf(e3.w, uv3.w, a);
        acc[i] = a;
    }

    // ---- LDS-transpose reduction ----
#pragma unroll
    for (int q = 0; q < ITER; ++q) red[wave][lane][q] = acc[q];
    __syncthreads();

    const int a    = lane & 31;
    const int base = (lane >> 5) * 32;
    float s = 0.f;
#pragma unroll
    for (int r = 0; r < 32; ++r) s += red[wave][base + r][a];
    s += __shfl_xor(s, 32);

    if (lane < 32) {
        scores[(size_t)b * L + l0 + lane] = s;
    }
}

// ---------------------------------------------------------------------------
// Kernel 3: in-place row softmax, one block (512 threads) per b, 1 float4/thr.
// ---------------------------------------------------------------------------
__global__ __launch_bounds__(512) void softmax_kernel(float* __restrict__ out) {
    __shared__ float redm[8];
    __shared__ float reds[8];
    const int b    = blockIdx.x;
    const int tid  = threadIdx.x;
    const int wave = tid >> 6;
    const int lane = tid & 63;

    float4* __restrict__ r4 = (float4*)(out + (size_t)b * L);
    float4 a = r4[tid];

    float m = fmaxf(fmaxf(a.x, a.y), fmaxf(a.z, a.w));
#pragma unroll
    for (int off = 32; off; off >>= 1) m = fmaxf(m, __shfl_down(m, off));
    if (lane == 0) redm[wave] = m;
    __syncthreads();
    m = fmaxf(fmaxf(fmaxf(redm[0], redm[1]), fmaxf(redm[2], redm[3])),
              fmaxf(fmaxf(redm[4], redm[5]), fmaxf(redm[6], redm[7])));

    float e0 = expf(a.x - m), e1 = expf(a.y - m);
    float e2 = expf(a.z - m), e3 = expf(a.w - m);

    float s = (e0 + e1) + (e2 + e3);
#pragma unroll
    for (int off = 32; off; off >>= 1) s += __shfl_down(s, off);
    if (lane == 0) reds[wave] = s;
    __syncthreads();
    s = ((reds[0] + reds[1]) + (reds[2] + reds[3])) +
        ((reds[4] + reds[5]) + (reds[6] + reds[7]));

    const float inv = 1.f / s;
    a.x = e0 * inv; a.y = e1 * inv; a.z = e2 * inv; a.w = e3 * inv;
    r4[tid] = a;
}

extern "C" void kernel_launch(void* const* d_in, const int* in_sizes, int n_in,
                              void* d_out, int out_size, void* d_ws, size_t ws_size,
                              hipStream_t stream) {
    const float* hidden = (const float*)d_in[0];  // [B, H]
    const float* enc    = (const float*)d_in[1];  // [L, B, H]
    const float* W      = (const float*)d_in[2];  // [H, H]
    // d_in[3] (bias) cancels in the softmax over l — provably irrelevant.

    float* u       = (float*)d_ws;                        // [B, H]      256 KB
    float* partial = (float*)d_ws + (size_t)B * H;        // [B, GC, H]  8 MB
    float* out     = (float*)d_out;                       // [B, 1, L]   fp32

    // 1) u = hidden @ W (partial + reduce)
    u_partial_kernel<<<dim3(GC, HC, BG), 256, 0, stream>>>(hidden, W, partial);
    u_reduce_kernel<<<(B * H) / 256, 256, 0, stream>>>(partial, u);

    // 2) scores[b,l] = dot(enc[l,b,:], u[b,:]) -> d_out
    scores_kernel<<<(B * L / ITER) / 4, 256, 0, stream>>>(
        (const f32x4*)enc, (const f32x4*)u, out);

    // 3) softmax over l, in place
    softmax_kernel<<<B, 512, 0, stream>>>(out);
}

// Round 8
// 100.656 us; speedup vs baseline: 3.0843x; 1.0035x over previous
//
#include <hip/hip_runtime.h>
#include <math.h>

#define H 1024
#define B 64
#define L 2048

#define GC 32   // g-chunks (32 g each)
#define HC 4    // h-chunks (256 h each)
#define BG 8    // b-groups (8 b per thread)

typedef float f32x4 __attribute__((ext_vector_type(4)));

// ---------------------------------------------------------------------------
// Kernel 1a: partial[b][gc][h] = sum_{g in chunk gc} hidden[b,g] * W[g,h]
// grid (GC, HC, BG) = 1024 blocks (4/CU). Thread owns one h, 8 b's in regs.
// 32 g-iters, unroll 8. hidden reads wave-uniform -> scalar loads.
// ---------------------------------------------------------------------------
__global__ __launch_bounds__(256) void u_partial_kernel(
        const float* __restrict__ hidden,
        const float* __restrict__ W,
        float* __restrict__ partial) {
    const int h  = blockIdx.y * 256 + threadIdx.x;
    const int g0 = blockIdx.x * 32;
    const int b0 = blockIdx.z * 8;

    float acc[8];
#pragma unroll
    for (int bb = 0; bb < 8; ++bb) acc[bb] = 0.f;

#pragma unroll 8
    for (int gg = 0; gg < 32; ++gg) {
        const int g = g0 + gg;
        const float w = W[(size_t)g * H + h];
#pragma unroll
        for (int bb = 0; bb < 8; ++bb) {
            acc[bb] = fmaf(hidden[(b0 + bb) * H + g], w, acc[bb]);
        }
    }

#pragma unroll
    for (int bb = 0; bb < 8; ++bb) {
        partial[((size_t)(b0 + bb) * GC + blockIdx.x) * H + h] = acc[bb];
    }
}

// ---------------------------------------------------------------------------
// Kernel 1b: u[b][h] = sum_gc partial[b][gc][h]. 8 MB read (L2-hot).
// ---------------------------------------------------------------------------
__global__ __launch_bounds__(256) void u_reduce_kernel(
        const float* __restrict__ partial,
        float* __restrict__ u) {
    const int idx = blockIdx.x * 256 + threadIdx.x;   // b*H + h
    const int b = idx >> 10;
    const int h = idx & (H - 1);
    float s = 0.f;
#pragma unroll 16
    for (int gc = 0; gc < GC; ++gc) {
        s += partial[((size_t)b * GC + gc) * H + h];
    }
    u[idx] = s;
}

// ---------------------------------------------------------------------------
// Kernel 2: scores[b,l] = dot(enc[l,b,:], u[b,:]).
// One wave: ITER=32 consecutive l's for fixed b; u row in 16 VGPRs; enc
// streamed non-temporal (zero reuse), unroll 4 -> 16 x 1 KB wave-loads in
// flight. Reduction via LDS transpose in a WAVE-PRIVATE tile: same-wave
// ds_write -> ds_read is ordered by the per-wave DS FIFO + lgkmcnt, so NO
// __syncthreads is needed (waves stay decoupled; compiler fence only).
// Lanes 0-31 then do one coalesced 128 B store.
// ---------------------------------------------------------------------------
#define ITER 32
__global__ __launch_bounds__(256, 4) void scores_kernel(
        const f32x4* __restrict__ enc4,
        const f32x4* __restrict__ u4,
        float* __restrict__ scores) {
    __shared__ float red[4][64][33];
    const int wave = threadIdx.x >> 6;
    const int lane = threadIdx.x & 63;
    const int gw   = blockIdx.x * 4 + wave;        // [0, B*L/ITER)
    const int b    = gw & (B - 1);
    const int l0   = (gw >> 6) * ITER;

    const f32x4* __restrict__ uu = u4 + (size_t)b * (H / 4);
    const f32x4 uv0 = uu[lane];
    const f32x4 uv1 = uu[64 + lane];
    const f32x4 uv2 = uu[128 + lane];
    const f32x4 uv3 = uu[192 + lane];

    const f32x4* __restrict__ e = enc4 + ((size_t)l0 * B + b) * (H / 4);

    float acc[ITER];
#pragma unroll 4
    for (int i = 0; i < ITER; ++i) {
        const f32x4* __restrict__ ei = e + (size_t)i * B * (H / 4);
        const f32x4 e0 = __builtin_nontemporal_load(ei + lane);
        const f32x4 e1 = __builtin_nontemporal_load(ei + 64 + lane);
        const f32x4 e2 = __builtin_nontemporal_load(ei + 128 + lane);
        const f32x4 e3 = __builtin_nontemporal_load(ei + 192 + lane);
        float a = e0.x * uv0.x;
        a = fmaf(e0.y, uv0.y, a);
        a = fmaf(e0.z, uv0.z, a);
        a = fmaf(e0.w, uv0.w, a);
        a = fmaf(e1.x, uv1.x, a);
        a = fmaf(e1.y, uv1.y, a);
        a = fmaf(e1.z, uv1.z, a);
        a = fmaf(e1.w, uv1.w, a);
        a = fmaf(e2.x, uv2.x, a);
        a = fmaf(e2.y, uv2.y, a);
        a = fmaf(e2.z, uv2.z, a);
        a = fmaf(e2.w, uv2.w, a);
        a = fmaf(e3.x, uv3.x, a);
        a = fmaf(e3.y, uv3.y, a);
        a = fmaf(e3.z, uv3.z, a);
        a = fmaf(e3.w, uv3.w, a);
        acc[i] = a;
    }

    // ---- LDS-transpose reduction (wave-private tile, no block barrier) ----
#pragma unroll
    for (int q = 0; q < ITER; ++q) red[wave][lane][q] = acc[q];
    asm volatile("" ::: "memory");   // compile-time order; HW: per-wave DS FIFO

    const int a    = lane & 31;
    const int base = (lane >> 5) * 32;
    float s = 0.f;
#pragma unroll
    for (int r = 0; r < 32; ++r) s += red[wave][base + r][a];
    s += __shfl_xor(s, 32);

    if (lane < 32) {
        scores[(size_t)b * L + l0 + lane] = s;
    }
}

// ---------------------------------------------------------------------------
// Kernel 3: in-place row softmax, one block (512 threads) per b, 1 float4/thr.
// ---------------------------------------------------------------------------
__global__ __launch_bounds__(512) void softmax_kernel(float* __restrict__ out) {
    __shared__ float redm[8];
    __shared__ float reds[8];
    const int b    = blockIdx.x;
    const int tid  = threadIdx.x;
    const int wave = tid >> 6;
    const int lane = tid & 63;

    float4* __restrict__ r4 = (float4*)(out + (size_t)b * L);
    float4 a = r4[tid];

    float m = fmaxf(fmaxf(a.x, a.y), fmaxf(a.z, a.w));
#pragma unroll
    for (int off = 32; off; off >>= 1) m = fmaxf(m, __shfl_down(m, off));
    if (lane == 0) redm[wave] = m;
    __syncthreads();
    m = fmaxf(fmaxf(fmaxf(redm[0], redm[1]), fmaxf(redm[2], redm[3])),
              fmaxf(fmaxf(redm[4], redm[5]), fmaxf(redm[6], redm[7])));

    float e0 = expf(a.x - m), e1 = expf(a.y - m);
    float e2 = expf(a.z - m), e3 = expf(a.w - m);

    float s = (e0 + e1) + (e2 + e3);
#pragma unroll
    for (int off = 32; off; off >>= 1) s += __shfl_down(s, off);
    if (lane == 0) reds[wave] = s;
    __syncthreads();
    s = ((reds[0] + reds[1]) + (reds[2] + reds[3])) +
        ((reds[4] + reds[5]) + (reds[6] + reds[7]));

    const float inv = 1.f / s;
    a.x = e0 * inv; a.y = e1 * inv; a.z = e2 * inv; a.w = e3 * inv;
    r4[tid] = a;
}

extern "C" void kernel_launch(void* const* d_in, const int* in_sizes, int n_in,
                              void* d_out, int out_size, void* d_ws, size_t ws_size,
                              hipStream_t stream) {
    const float* hidden = (const float*)d_in[0];  // [B, H]
    const float* enc    = (const float*)d_in[1];  // [L, B, H]
    const float* W      = (const float*)d_in[2];  // [H, H]
    // d_in[3] (bias) cancels in the softmax over l — provably irrelevant.

    float* u       = (float*)d_ws;                        // [B, H]      256 KB
    float* partial = (float*)d_ws + (size_t)B * H;        // [B, GC, H]  8 MB
    float* out     = (float*)d_out;                       // [B, 1, L]   fp32

    // 1) u = hidden @ W (partial + reduce)
    u_partial_kernel<<<dim3(GC, HC, BG), 256, 0, stream>>>(hidden, W, partial);
    u_reduce_kernel<<<(B * H) / 256, 256, 0, stream>>>(partial, u);

    // 2) scores[b,l] = dot(enc[l,b,:], u[b,:]) -> d_out
    scores_kernel<<<(B * L / ITER) / 4, 256, 0, stream>>>(
        (const f32x4*)enc, (const f32x4*)u, out);

    // 3) softmax over l, in place
    softmax_kernel<<<B, 512, 0, stream>>>(out);
}

// Round 9
// 96.219 us; speedup vs baseline: 3.2265x; 1.0461x over previous
//
#include <hip/hip_runtime.h>
#include <math.h>

#define H 1024
#define B 64
#define L 2048

#define GC 8    // g-chunks (128 g each) — summed in the scores prologue
#define HC 4    // h-chunks (256 h each)
#define BG 16   // b-groups (4 b per thread)

typedef float f32x4 __attribute__((ext_vector_type(4)));

// ---------------------------------------------------------------------------
// Kernel 1: partial[b][gc][h] = sum_{g in chunk gc} hidden[b,g] * W[g,h]
// grid (GC, HC, BG) = 512 blocks (2/CU). Thread owns one h, 4 b's in regs.
// 128 g-iters, unroll 8 -> 16 stall groups, hidden via wave-uniform scalar
// loads. partial is only 2 MB -> stays L2-resident for the scores prologue.
// NO u_reduce kernel: the scores kernel sums the GC=8 chunks itself.
// ---------------------------------------------------------------------------
__global__ __launch_bounds__(256) void u_partial_kernel(
        const float* __restrict__ hidden,
        const float* __restrict__ W,
        float* __restrict__ partial) {
    const int h  = blockIdx.y * 256 + threadIdx.x;
    const int g0 = blockIdx.x * 128;
    const int b0 = blockIdx.z * 4;

    float acc[4];
#pragma unroll
    for (int bb = 0; bb < 4; ++bb) acc[bb] = 0.f;

#pragma unroll 8
    for (int gg = 0; gg < 128; ++gg) {
        const int g = g0 + gg;
        const float w = W[(size_t)g * H + h];
#pragma unroll
        for (int bb = 0; bb < 4; ++bb) {
            acc[bb] = fmaf(hidden[(b0 + bb) * H + g], w, acc[bb]);
        }
    }

#pragma unroll
    for (int bb = 0; bb < 4; ++bb) {
        partial[((size_t)(b0 + bb) * GC + blockIdx.x) * H + h] = acc[bb];
    }
}

// ---------------------------------------------------------------------------
// Kernel 2: scores[b,l] = dot(enc[l,b,:], u[b,:]) with u materialized in the
// prologue: u-fragment (16 VGPRs) = sum over GC=8 L2-hot partial chunks.
// Stream phase unchanged from R8 (ITER=32, nt loads, wave-private LDS
// transpose reduction, no block barrier, coalesced 128 B store).
// ---------------------------------------------------------------------------
#define ITER 32
__global__ __launch_bounds__(256, 4) void scores_kernel(
        const f32x4* __restrict__ enc4,
        const f32x4* __restrict__ partial4,
        float* __restrict__ scores) {
    __shared__ float red[4][64][33];
    const int wave = threadIdx.x >> 6;
    const int lane = threadIdx.x & 63;
    const int gw   = blockIdx.x * 4 + wave;        // [0, B*L/ITER)
    const int b    = gw & (B - 1);
    const int l0   = (gw >> 6) * ITER;

    // ---- prologue: u[b, lane-slice] = sum_gc partial[b][gc][slice] ----
    const f32x4* __restrict__ pb = partial4 + (size_t)b * GC * (H / 4);
    f32x4 uv0 = pb[lane];
    f32x4 uv1 = pb[64 + lane];
    f32x4 uv2 = pb[128 + lane];
    f32x4 uv3 = pb[192 + lane];
#pragma unroll
    for (int gc = 1; gc < GC; ++gc) {
        const f32x4* __restrict__ pc = pb + (size_t)gc * (H / 4);
        uv0 += pc[lane];
        uv1 += pc[64 + lane];
        uv2 += pc[128 + lane];
        uv3 += pc[192 + lane];
    }

    const f32x4* __restrict__ e = enc4 + ((size_t)l0 * B + b) * (H / 4);

    float acc[ITER];
#pragma unroll 4
    for (int i = 0; i < ITER; ++i) {
        const f32x4* __restrict__ ei = e + (size_t)i * B * (H / 4);
        const f32x4 e0 = __builtin_nontemporal_load(ei + lane);
        const f32x4 e1 = __builtin_nontemporal_load(ei + 64 + lane);
        const f32x4 e2 = __builtin_nontemporal_load(ei + 128 + lane);
        const f32x4 e3 = __builtin_nontemporal_load(ei + 192 + lane);
        float a = e0.x * uv0.x;
        a = fmaf(e0.y, uv0.y, a);
        a = fmaf(e0.z, uv0.z, a);
        a = fmaf(e0.w, uv0.w, a);
        a = fmaf(e1.x, uv1.x, a);
        a = fmaf(e1.y, uv1.y, a);
        a = fmaf(e1.z, uv1.z, a);
        a = fmaf(e1.w, uv1.w, a);
        a = fmaf(e2.x, uv2.x, a);
        a = fmaf(e2.y, uv2.y, a);
        a = fmaf(e2.z, uv2.z, a);
        a = fmaf(e2.w, uv2.w, a);
        a = fmaf(e3.x, uv3.x, a);
        a = fmaf(e3.y, uv3.y, a);
        a = fmaf(e3.z, uv3.z, a);
        a = fmaf(e3.w, uv3.w, a);
        acc[i] = a;
    }

    // ---- LDS-transpose reduction (wave-private tile, no block barrier) ----
#pragma unroll
    for (int q = 0; q < ITER; ++q) red[wave][lane][q] = acc[q];
    asm volatile("" ::: "memory");   // compile-time order; HW: per-wave DS FIFO

    const int a    = lane & 31;
    const int base = (lane >> 5) * 32;
    float s = 0.f;
#pragma unroll
    for (int r = 0; r < 32; ++r) s += red[wave][base + r][a];
    s += __shfl_xor(s, 32);

    if (lane < 32) {
        scores[(size_t)b * L + l0 + lane] = s;
    }
}

// ---------------------------------------------------------------------------
// Kernel 3: in-place row softmax, one block (512 threads) per b, 1 float4/thr.
// ---------------------------------------------------------------------------
__global__ __launch_bounds__(512) void softmax_kernel(float* __restrict__ out) {
    __shared__ float redm[8];
    __shared__ float reds[8];
    const int b    = blockIdx.x;
    const int tid  = threadIdx.x;
    const int wave = tid >> 6;
    const int lane = tid & 63;

    float4* __restrict__ r4 = (float4*)(out + (size_t)b * L);
    float4 a = r4[tid];

    float m = fmaxf(fmaxf(a.x, a.y), fmaxf(a.z, a.w));
#pragma unroll
    for (int off = 32; off; off >>= 1) m = fmaxf(m, __shfl_down(m, off));
    if (lane == 0) redm[wave] = m;
    __syncthreads();
    m = fmaxf(fmaxf(fmaxf(redm[0], redm[1]), fmaxf(redm[2], redm[3])),
              fmaxf(fmaxf(redm[4], redm[5]), fmaxf(redm[6], redm[7])));

    float e0 = expf(a.x - m), e1 = expf(a.y - m);
    float e2 = expf(a.z - m), e3 = expf(a.w - m);

    float s = (e0 + e1) + (e2 + e3);
#pragma unroll
    for (int off = 32; off; off >>= 1) s += __shfl_down(s, off);
    if (lane == 0) reds[wave] = s;
    __syncthreads();
    s = ((reds[0] + reds[1]) + (reds[2] + reds[3])) +
        ((reds[4] + reds[5]) + (reds[6] + reds[7]));

    const float inv = 1.f / s;
    a.x = e0 * inv; a.y = e1 * inv; a.z = e2 * inv; a.w = e3 * inv;
    r4[tid] = a;
}

extern "C" void kernel_launch(void* const* d_in, const int* in_sizes, int n_in,
                              void* d_out, int out_size, void* d_ws, size_t ws_size,
                              hipStream_t stream) {
    const float* hidden = (const float*)d_in[0];  // [B, H]
    const float* enc    = (const float*)d_in[1];  // [L, B, H]
    const float* W      = (const float*)d_in[2];  // [H, H]
    // d_in[3] (bias) cancels in the softmax over l — provably irrelevant.

    float* partial = (float*)d_ws;                        // [B, GC, H]  2 MB
    float* out     = (float*)d_out;                       // [B, 1, L]   fp32

    // 1) partial = split-K hidden @ W (GC=8 chunks; summed in scores prologue)
    u_partial_kernel<<<dim3(GC, HC, BG), 256, 0, stream>>>(hidden, W, partial);

    // 2) scores[b,l] = dot(enc[l,b,:], sum_gc partial[b][gc][:]) -> d_out
    scores_kernel<<<(B * L / ITER) / 4, 256, 0, stream>>>(
        (const f32x4*)enc, (const f32x4*)partial, out);

    // 3) softmax over l, in place
    softmax_kernel<<<B, 512, 0, stream>>>(out);
}